// Round 1
// baseline (13219.525 us; speedup 1.0000x reference)
//
#include <hip/hip_runtime.h>
#include <hip/hip_bf16.h>
#include <math.h>

// Problem constants
#define B   32
#define T   64
#define E   512
#define H   1024
#define V   32000
#define G3  3072            // 3*H
#define TV  (T*V)           // 2048000
#define BTV ((size_t)B*T*V) // 65536000
#define SOS 1
#define NVB 250             // logits v-blocks of 128

// ws layout (float offsets)
#define WS_H0   0          // 2 * B*H (ping-pong)
#define WS_H1   65536      // 2 * B*H
#define WS_GI0  131072     // B*3H
#define WS_GH0  229376
#define WS_GI1  327680
#define WS_GH1  425984
#define WS_PM   524288     // B*NVB
#define WS_PS   532288
#define WS_PI   540288     // ints
#define WS_TOK  548288     // (T+1)*B ints

__global__ __launch_bounds__(256) void init_kernel(
    const float* __restrict__ ehid, float* __restrict__ h0,
    float* __restrict__ h1, int* __restrict__ tok0)
{
    int idx = blockIdx.x * 256 + threadIdx.x;   // 0..65535
    if (idx < B * H) h0[idx] = ehid[idx];
    else             h1[idx - B * H] = ehid[idx];
    if (idx < B) tok0[idx] = SOS;
}

// G = A @ W^T for a [B, 3H] gate pre-activation. blocks 0..95 -> Gi, 96..191 -> Gh.
// For layer 0's Gi, A==nullptr means gather rows from embedding via tok.
__global__ __launch_bounds__(256) void gates_kernel(
    const float* __restrict__ Agi, const float* __restrict__ emb,
    const int* __restrict__ tok, const float* __restrict__ Agh,
    const float* __restrict__ Wih, int Kgi, const float* __restrict__ Whh,
    float* __restrict__ Gi, float* __restrict__ Gh)
{
    const int tid = threadIdx.x;
    const bool isGh = blockIdx.x >= 96;
    const int ntile = isGh ? (blockIdx.x - 96) : blockIdx.x;
    const float* W = isGh ? Whh : Wih;
    const float* A = isGh ? Agh : Agi;
    float* G = isGh ? Gh : Gi;
    const int K = isGh ? H : Kgi;
    const bool gather = (!isGh) && (A == nullptr);

    __shared__ float4 As4[B][17];     // 32 x 64 floats (+1 f4 pad)
    __shared__ float4 Ws4[32][17];
    __shared__ int stok[B];
    if (gather && tid < B) stok[tid] = tok[tid];
    __syncthreads();

    const int tx = tid & 15, ty = tid >> 4;
    const int b0 = 2 * tx, n0 = 2 * ty;
    float acc00 = 0.f, acc01 = 0.f, acc10 = 0.f, acc11 = 0.f;

    for (int kc = 0; kc < K; kc += 64) {
        for (int u = tid; u < 32 * 16; u += 256) {
            int row = u >> 4, c = u & 15;
            const float* src = gather ? (emb + (size_t)stok[row] * E)
                                      : (A + (size_t)row * K);
            As4[row][c] = *(const float4*)(src + kc + c * 4);
        }
        for (int u = tid; u < 32 * 16; u += 256) {
            int row = u >> 4, c = u & 15;
            Ws4[row][c] = *(const float4*)(W + (size_t)(ntile * 32 + row) * K + kc + c * 4);
        }
        __syncthreads();
        #pragma unroll
        for (int kq = 0; kq < 16; ++kq) {
            float4 a0 = As4[b0][kq], a1 = As4[b0 + 1][kq];
            float4 w0 = Ws4[n0][kq], w1 = Ws4[n0 + 1][kq];
            acc00 += a0.x*w0.x + a0.y*w0.y + a0.z*w0.z + a0.w*w0.w;
            acc01 += a0.x*w1.x + a0.y*w1.y + a0.z*w1.z + a0.w*w1.w;
            acc10 += a1.x*w0.x + a1.y*w0.y + a1.z*w0.z + a1.w*w0.w;
            acc11 += a1.x*w1.x + a1.y*w1.y + a1.z*w1.z + a1.w*w1.w;
        }
        __syncthreads();
    }
    const int ng = ntile * 32 + n0;
    G[(size_t)(b0    ) * G3 + ng    ] = acc00;
    G[(size_t)(b0    ) * G3 + ng + 1] = acc01;
    G[(size_t)(b0 + 1) * G3 + ng    ] = acc10;
    G[(size_t)(b0 + 1) * G3 + ng + 1] = acc11;
}

// PyTorch GRU cell combine: gates (r,z,n) at cols j, j+H, j+2H.
__global__ __launch_bounds__(256) void gru_combine(
    const float* __restrict__ Gi, const float* __restrict__ Gh,
    const float* __restrict__ bih, const float* __restrict__ bhh,
    const float* __restrict__ hold, float* __restrict__ hnew,
    float* __restrict__ fin)
{
    int idx = blockIdx.x * 256 + threadIdx.x;   // 0..32767
    int b = idx >> 10, j = idx & 1023;
    size_t g = (size_t)b * G3 + j;
    float ir = Gi[g]         + bih[j];
    float hr = Gh[g]         + bhh[j];
    float iz = Gi[g + H]     + bih[j + H];
    float hz = Gh[g + H]     + bhh[j + H];
    float in_ = Gi[g + 2*H]  + bih[j + 2*H];
    float hn  = Gh[g + 2*H]  + bhh[j + 2*H];
    float r = 1.f / (1.f + expf(-(ir + hr)));
    float z = 1.f / (1.f + expf(-(iz + hz)));
    float n = tanhf(in_ + r * hn);
    float hv = (1.f - z) * n + z * hold[idx];
    hnew[idx] = hv;
    if (fin) fin[idx] = hv;
}

// logits tile: 32 b x 128 v per block, raw logits -> out, online-softmax partials -> pm/ps/pidx
__global__ __launch_bounds__(256) void logits_kernel(
    const float* __restrict__ h1, const float* __restrict__ wout,
    const float* __restrict__ bout, float* __restrict__ out, int t,
    float* __restrict__ pm, float* __restrict__ ps, int* __restrict__ pidx)
{
    const int tid = threadIdx.x, blk = blockIdx.x;
    const int tx = tid & 7, ty = tid >> 3;   // rows 4tx.., cols 4ty..
    __shared__ float4 As4[B][9];
    __shared__ float4 Ws4[128][9];
    float acc[4][4] = {};

    for (int kc = 0; kc < H; kc += 32) {
        {   // A: 32 rows x 8 float4 = exactly 256
            int row = tid >> 3, c = tid & 7;
            As4[row][c] = *(const float4*)(h1 + (size_t)row * H + kc + c * 4);
        }
        for (int u = tid; u < 128 * 8; u += 256) {
            int row = u >> 3, c = u & 7;
            Ws4[row][c] = *(const float4*)(wout + (size_t)(blk * 128 + row) * H + kc + c * 4);
        }
        __syncthreads();
        #pragma unroll
        for (int kq = 0; kq < 8; ++kq) {
            float4 a[4], w[4];
            #pragma unroll
            for (int i = 0; i < 4; ++i) a[i] = As4[4 * tx + i][kq];
            #pragma unroll
            for (int j = 0; j < 4; ++j) w[j] = Ws4[4 * ty + j][kq];
            #pragma unroll
            for (int i = 0; i < 4; ++i)
                #pragma unroll
                for (int j = 0; j < 4; ++j)
                    acc[i][j] += a[i].x*w[j].x + a[i].y*w[j].y + a[i].z*w[j].z + a[i].w*w[j].w;
        }
        __syncthreads();
    }

    const int vbase = blk * 128 + 4 * ty;
    #pragma unroll
    for (int j = 0; j < 4; ++j) {
        float bb = bout[vbase + j];
        #pragma unroll
        for (int i = 0; i < 4; ++i) {
            acc[i][j] += bb;
            out[(size_t)(4 * tx + i) * TV + (size_t)t * V + vbase + j] = acc[i][j];
        }
    }

    // per-block per-row partials: max, argmax (first occurrence), sum exp(l - max)
    __shared__ float rm[8][32];
    __shared__ int   ri[8][32];
    __shared__ float rs[8][32];
    __shared__ float Mrow[8];
    __shared__ int   Irow[8];
    for (int i = 0; i < 4; ++i) {
        int r = 4 * tx + i;
        float m = acc[i][0]; int mi = 0;
        #pragma unroll
        for (int j = 1; j < 4; ++j) if (acc[i][j] > m) { m = acc[i][j]; mi = j; }
        rm[tx][ty] = m; ri[tx][ty] = vbase + mi;
        __syncthreads();
        if (ty == 0) {
            float M = rm[tx][0]; int I = ri[tx][0];
            for (int u = 1; u < 32; ++u)
                if (rm[tx][u] > M) { M = rm[tx][u]; I = ri[tx][u]; }
            Mrow[tx] = M; Irow[tx] = I;
        }
        __syncthreads();
        float M = Mrow[tx];
        float s = 0.f;
        #pragma unroll
        for (int j = 0; j < 4; ++j) s += expf(acc[i][j] - M);
        rs[tx][ty] = s;
        __syncthreads();
        if (ty == 0) {
            float S = 0.f;
            for (int u = 0; u < 32; ++u) S += rs[tx][u];
            pm[(size_t)r * NVB + blk] = M;
            ps[(size_t)r * NVB + blk] = S;
            pidx[(size_t)r * NVB + blk] = Irow[tx];
        }
        __syncthreads();
    }
}

// merge partials for one row (redundantly per chunk-block), write next token, subtract lse
__global__ __launch_bounds__(256) void finalize_kernel(
    float* __restrict__ out, int t,
    const float* __restrict__ pm, const float* __restrict__ ps,
    const int* __restrict__ pidx, int* __restrict__ tok_next)
{
    const int row = blockIdx.y, chunk = blockIdx.x, tid = threadIdx.x;
    __shared__ float sm[256];
    __shared__ float ss[256];
    __shared__ int   si[256];
    float m = -INFINITY, s = 0.f; int ix = 0x7fffffff;
    if (tid < NVB) {
        m  = pm[(size_t)row * NVB + tid];
        s  = ps[(size_t)row * NVB + tid];
        ix = pidx[(size_t)row * NVB + tid];
    }
    sm[tid] = m; ss[tid] = s; si[tid] = ix;
    __syncthreads();
    for (int off = 128; off > 0; off >>= 1) {
        if (tid < off) {
            float ma = sm[tid], mb = sm[tid + off];
            float sa = ss[tid], sb = ss[tid + off];
            int   ia = si[tid], ib = si[tid + off];
            if (mb > ma || (mb == ma && ib < ia)) si[tid] = ib;
            float M, S;
            if (mb == -INFINITY)      { M = ma; S = sa; }
            else if (ma == -INFINITY) { M = mb; S = sb; }
            else {
                M = fmaxf(ma, mb);
                S = sa * expf(ma - M) + sb * expf(mb - M);
            }
            sm[tid] = M; ss[tid] = S;
        }
        __syncthreads();
    }
    __shared__ float slse;
    if (tid == 0) {
        slse = sm[0] + logf(ss[0]);
        if (chunk == 0) tok_next[row] = si[0];
    }
    __syncthreads();
    float lse = slse;
    size_t base = (size_t)row * TV + (size_t)t * V + (size_t)chunk * 1024;
    int lim = V - chunk * 1024; if (lim > 1024) lim = 1024;
    for (int i = tid; i < lim; i += 256) out[base + i] -= lse;
}

extern "C" void kernel_launch(void* const* d_in, const int* in_sizes, int n_in,
                              void* d_out, int out_size, void* d_ws, size_t ws_size,
                              hipStream_t stream)
{
    const float* enc_hid = (const float*)d_in[1];
    const float* emb     = (const float*)d_in[2];
    const float* w_ih0   = (const float*)d_in[3];
    const float* w_hh0   = (const float*)d_in[4];
    const float* b_ih0   = (const float*)d_in[5];
    const float* b_hh0   = (const float*)d_in[6];
    const float* w_ih1   = (const float*)d_in[7];
    const float* w_hh1   = (const float*)d_in[8];
    const float* b_ih1   = (const float*)d_in[9];
    const float* b_hh1   = (const float*)d_in[10];
    const float* w_out   = (const float*)d_in[11];
    const float* b_out   = (const float*)d_in[12];

    float* out = (float*)d_out;
    float* ws  = (float*)d_ws;

    float* H0  = ws + WS_H0;
    float* H1  = ws + WS_H1;
    float* GI0 = ws + WS_GI0;
    float* GH0 = ws + WS_GH0;
    float* GI1 = ws + WS_GI1;
    float* GH1 = ws + WS_GH1;
    float* PM  = ws + WS_PM;
    float* PS  = ws + WS_PS;
    int*   PI  = (int*)(ws + WS_PI);
    int*   TOK = (int*)(ws + WS_TOK);

    init_kernel<<<256, 256, 0, stream>>>(enc_hid, H0, H1, TOK);

    for (int t = 0; t < T; ++t) {
        float* h0o = H0 + (t & 1) * (B * H);
        float* h0n = H0 + ((t + 1) & 1) * (B * H);
        float* h1o = H1 + (t & 1) * (B * H);
        float* h1n = H1 + ((t + 1) & 1) * (B * H);
        const int* tok_t = TOK + t * B;

        // layer 0 gates: gi = embed[tok] @ w_ih0^T (K=512), gh = h0 @ w_hh0^T (K=1024)
        gates_kernel<<<192, 256, 0, stream>>>(nullptr, emb, tok_t, h0o,
                                              w_ih0, E, w_hh0, GI0, GH0);
        gru_combine<<<128, 256, 0, stream>>>(GI0, GH0, b_ih0, b_hh0, h0o, h0n,
                                             (t == T - 1) ? (out + BTV) : nullptr);
        // layer 1 gates: gi = h0_new @ w_ih1^T (K=1024), gh = h1 @ w_hh1^T
        gates_kernel<<<192, 256, 0, stream>>>(h0n, nullptr, nullptr, h1o,
                                              w_ih1, H, w_hh1, GI1, GH1);
        gru_combine<<<128, 256, 0, stream>>>(GI1, GH1, b_ih1, b_hh1, h1o, h1n,
                                             (t == T - 1) ? (out + BTV + B * H) : nullptr);
        // logits + partials
        logits_kernel<<<NVB, 256, 0, stream>>>(h1n, w_out, b_out, out, t, PM, PS, PI);
        // argmax/lse merge + log_softmax subtract + next token
        finalize_kernel<<<dim3(32, 32), 256, 0, stream>>>(out, t, PM, PS, PI,
                                                          TOK + (t + 1) * B);
    }
}